// Round 7
// baseline (165.127 us; speedup 1.0000x reference)
//
#include <hip/hip_runtime.h>

#define PATCH 32
#define PPB   32                      // patches per block
#define FLAGRDY   0x40000000
#define READYMASK 0xC0000000          // 0xAAAAAAAA poison (bit31=1) and 0 both decode "not ready"
#define SUMMASK   0x00FFFFFF

typedef float f4 __attribute__((ext_vector_type(4)));

__device__ __forceinline__ f4 to_f4(const float4 v) {
    f4 r; r.x = v.x; r.y = v.y; r.z = v.z; r.w = v.w; return r;
}

// value of flat xf element k (k in [0, bs*96)) for this block
__device__ __forceinline__ float xf_val(int k, const int* sRow, const float* shxm) {
    const int row = (int)((unsigned)k / 96u);
    const int rem = k - row * 96;
    const int l = rem >> 5, t = rem & 31;
    const int rp = sRow[row];
    const int jq = rp >> 4, c = (rp >> 2) & 3, v = rp & 3;
    const int sz = PATCH >> v;
    const bool nz = (l == v)     ? ((unsigned)(t - c * sz) < (unsigned)sz)
                  : (l + 1 == v) ? ((unsigned)(t - (c >> 1) * (sz << 1)) < (unsigned)(sz << 1))
                                 : false;
    return nz ? shxm[jq * PATCH + t] : 0.f;
}

// ---------------------------------------------------------------------------
// Single fused kernel: gate + softmax + top-2 + scan + decoupled lookback +
// emit. 2048 blocks x 256 threads, 32 patches/block, 6 blocks/CU.
// Emit sources from LDS only. xf stream is emitted with an explicit 16B
// alignment phase so no dwordx4 store ever straddles (o_xf base = out+69T
// floats is 16B-aligned only when T%4==0).
// ---------------------------------------------------------------------------
__global__ __launch_bounds__(256, 6) void k_fused(
    const float* __restrict__ x, const float* __restrict__ mask,
    const float* __restrict__ Wg,
    int* __restrict__ flags, const long T,
    float* __restrict__ o_newx, float* __restrict__ o_newm,
    float* __restrict__ o_size, float* __restrict__ o_w,
    float* __restrict__ o_eidx, float* __restrict__ o_xf)
{
    __shared__ float sw[128];
    __shared__ float shx [PPB * PATCH];   // x tile
    __shared__ float shm [PPB * PATCH];   // mask tile
    __shared__ float shxm[PPB * PATCH];   // x*mask tile
    __shared__ int   sMeta[PPB];          // b0 | b1<<4 | v<<8
    __shared__ float sW0[PPB], sW1[PPB];
    __shared__ int   sCnt[PPB];
    __shared__ int   sRow[PPB * 4];       // per-row: jq<<4 | c<<2 | v
    __shared__ int   sOffS, sTot;

    const int tid = threadIdx.x;
    const int bid = blockIdx.x;
    if (tid < 128) sw[tid] = Wg[tid];
    if (tid == 0) sOffS = 0;

    // ---- stage tiles: one float4 of x and mask per thread ----
    const long pbase = (long)bid * (PPB * PATCH);
    const float4 xq = *(const float4*)(x + pbase + tid * 4);
    const float4 mq = *(const float4*)(mask + pbase + tid * 4);
    ((f4*)shx)[tid] = to_f4(xq);
    ((f4*)shm)[tid] = to_f4(mq);
    f4 xm; xm.x = xq.x * mq.x; xm.y = xq.y * mq.y;
    xm.z = xq.z * mq.z; xm.w = xq.w * mq.w;
    ((f4*)shxm)[tid] = xm;
    __syncthreads();                      // sw (and tiles) ready

    // ---- gate: 8 threads/patch, shfl_xor butterfly over the 8 quarters ----
    const int jp = tid >> 3, sub = tid & 7;
    const int k4 = sub * 4;
    float z0 = fmaf(xq.x, sw[k4],    fmaf(xq.y, sw[k4+1],    fmaf(xq.z, sw[k4+2],    xq.w * sw[k4+3])));
    float z1 = fmaf(xq.x, sw[32+k4], fmaf(xq.y, sw[32+k4+1], fmaf(xq.z, sw[32+k4+2], xq.w * sw[32+k4+3])));
    float z2 = fmaf(xq.x, sw[64+k4], fmaf(xq.y, sw[64+k4+1], fmaf(xq.z, sw[64+k4+2], xq.w * sw[64+k4+3])));
    float z3 = fmaf(xq.x, sw[96+k4], fmaf(xq.y, sw[96+k4+1], fmaf(xq.z, sw[96+k4+2], xq.w * sw[96+k4+3])));
    #pragma unroll
    for (int mm = 1; mm < 8; mm <<= 1) {
        z0 += __shfl_xor(z0, mm);
        z1 += __shfl_xor(z1, mm);
        z2 += __shfl_xor(z2, mm);
        z3 += __shfl_xor(z3, mm);
    }
    if (sub == 0) {
        const float zm = fmaxf(fmaxf(z0, z1), fmaxf(z2, z3));
        const float e0 = expf(z0 - zm), e1 = expf(z1 - zm),
                    e2 = expf(z2 - zm), e3 = expf(z3 - zm);
        const float s = e0 + e1 + e2 + e3;
        float pv[4];
        pv[0] = e0 / s; pv[1] = e1 / s; pv[2] = e2 / s; pv[3] = e3 / s;

        int b0 = 0; float v0 = pv[0];
        #pragma unroll
        for (int i = 1; i < 4; i++) if (pv[i] > v0) { v0 = pv[i]; b0 = i; }
        int b1 = -1; float v1 = -1.f;
        #pragma unroll
        for (int i = 0; i < 4; i++) if (i != b0 && pv[i] > v1) { v1 = pv[i]; b1 = i; }

        const int m0 = (b0 < 3) ? b0 : -1;
        const int m1 = (b1 < 3) ? b1 : -1;
        int lv = m0 > m1 ? m0 : m1;
        if (lv < 0) lv = 0;

        sMeta[jp] = b0 | (b1 << 4) | (lv << 8);
        sW0[jp] = v0;
        sW1[jp] = v1;
        sCnt[jp] = 1 << lv;
    }
    __syncthreads();

    // ---- wave 0: scan of 32 counts, publish flag, build row descriptors ----
    if (tid < PPB) {
        const int c = sCnt[tid];
        int inc = c;
        #pragma unroll
        for (int d = 1; d < PPB; d <<= 1) {
            const int t = __shfl_up(inc, d);
            if (tid >= d) inc += t;
        }
        const int lst = inc - c;
        if (tid == PPB - 1) {
            sTot = inc;
            __hip_atomic_store(&flags[bid], FLAGRDY | inc,
                               __ATOMIC_RELAXED, __HIP_MEMORY_SCOPE_AGENT);
        }
        const int v = (sMeta[tid] >> 8) & 15;
        for (int c2 = 0; c2 < c; c2++)
            sRow[lst + c2] = (tid << 4) | (c2 << 2) | v;
    }

    // ---- decoupled lookback over predecessor flags (all 256 threads) ----
    int acc = 0;
    for (int b = tid; b < bid; b += 256) {
        int f;
        while (((f = __hip_atomic_load(&flags[b], __ATOMIC_RELAXED,
                                       __HIP_MEMORY_SCOPE_AGENT)) & READYMASK) != FLAGRDY)
            __builtin_amdgcn_s_sleep(2);
        acc += f & SUMMASK;
    }
    #pragma unroll
    for (int off = 32; off >= 1; off >>= 1) acc += __shfl_down(acc, off);
    if ((tid & 63) == 0 && acc) atomicAdd(&sOffS, acc);
    __syncthreads();

    const int  bs = sTot;             // rows this block emits (<= 128)
    const long R0 = sOffS;            // global row offset

    // ---- small streams: size / weights / expert_idx ----
    for (int g = tid; g < bs; g += 256) {
        const int v = sRow[g] & 3;
        __builtin_nontemporal_store((float)(PATCH >> v), &o_size[R0 + g]);
    }
    for (int g = tid; g < 2 * bs; g += 256) {
        const int row = g >> 1, k = g & 1;
        const int jq = sRow[row] >> 4;
        const int mt = sMeta[jq];
        const float wv = k ? sW1[jq] : sW0[jq];
        const float ev = (float)(k ? ((mt >> 4) & 15) : (mt & 15));
        __builtin_nontemporal_store(wv, &o_w[R0 * 2 + g]);
        __builtin_nontemporal_store(ev, &o_eidx[R0 * 2 + g]);
    }

    // ---- new_x / new_mask: bs rows x 8 f4 (bases 16B-aligned for any T) ----
    f4* __restrict__ onx = (f4*)o_newx + R0 * 8;
    f4* __restrict__ onm = (f4*)o_newm + R0 * 8;
    for (int g = tid; g < bs * 8; g += 256) {
        const int row = g >> 3, q = g & 7;
        const int rp = sRow[row];
        const int jq = rp >> 4, c = (rp >> 2) & 3, v = rp & 3;
        const int sz = PATCH >> v;
        f4 vx = {0.f, 0.f, 0.f, 0.f}, vm = {0.f, 0.f, 0.f, 0.f};
        if (4 * q < sz) {
            const int a = jq * PATCH + c * sz + 4 * q;
            vx = *(const f4*)&shx[a];
            vm = *(const f4*)&shm[a];
        }
        __builtin_nontemporal_store(vx, &onx[g]);
        __builtin_nontemporal_store(vm, &onm[g]);
    }

    // ---- x_final: flat [0, bs*96) floats, stores realigned to 16B ----
    float* __restrict__ xfb = o_xf + R0 * 96;     // abs float offset 69T + R0*96
    const int pad = (int)((4 - (T & 3)) & 3);     // 69T ≡ T (mod 4)
    const int nk = bs * 96;
    if (pad == 0) {
        // fast path: base already 16B-aligned, b128 LDS gather
        f4* __restrict__ oxf = (f4*)xfb;
        for (int g = tid; g < bs * 24; g += 256) {
            const int row = g / 24;
            const int rem = g - row * 24;
            const int l = rem >> 3, q = rem & 7;
            const int rp = sRow[row];
            const int jq = rp >> 4, c = (rp >> 2) & 3, v = rp & 3;
            const int sz = PATCH >> v;
            const int t4 = 4 * q;
            const int lo_own = c * sz;
            const int lo_par = (c >> 1) * (sz << 1);
            const bool nz = (l == v)     ? ((unsigned)(t4 - lo_own) < (unsigned)sz)
                          : (l + 1 == v) ? ((unsigned)(t4 - lo_par) < (unsigned)(sz << 1))
                                         : false;
            const f4 src = *(const f4*)&shxm[jq * PATCH + t4];
            f4 o;
            o.x = nz ? src.x : 0.f; o.y = nz ? src.y : 0.f;
            o.z = nz ? src.z : 0.f; o.w = nz ? src.w : 0.f;
            __builtin_nontemporal_store(o, &oxf[g]);
        }
    } else {
        // head dwords so that f4 groups start at abs-16B boundaries
        if (tid < pad)
            __builtin_nontemporal_store(xf_val(tid, sRow, shxm), &xfb[tid]);
        const int nbody = (nk - pad) >> 2;
        for (int j = tid; j < nbody; j += 256) {
            const int k0 = pad + 4 * j;
            const int row0 = (int)((unsigned)k0 / 96u);
            const int rem0 = k0 - row0 * 96;
            f4 o;
            if (rem0 <= 92) {                      // whole group in one row
                const int rp = sRow[row0];
                const int jq = rp >> 4, c = (rp >> 2) & 3, v = rp & 3;
                const int sz = PATCH >> v;
                const int base = jq * PATCH;
                #pragma unroll
                for (int e = 0; e < 4; e++) {
                    const int rem = rem0 + e;
                    const int l = rem >> 5, t = rem & 31;
                    const bool nz = (l == v)     ? ((unsigned)(t - c * sz) < (unsigned)sz)
                                  : (l + 1 == v) ? ((unsigned)(t - (c >> 1) * (sz << 1)) < (unsigned)(sz << 1))
                                                 : false;
                    ((float*)&o)[e] = nz ? shxm[base + t] : 0.f;
                }
            } else {                               // group straddles a row
                #pragma unroll
                for (int e = 0; e < 4; e++)
                    ((float*)&o)[e] = xf_val(k0 + e, sRow, shxm);
            }
            __builtin_nontemporal_store(o, (f4*)(xfb + k0));
        }
        const int tstart = pad + 4 * nbody;        // tail dwords (<4)
        if (tid < nk - tstart)
            __builtin_nontemporal_store(xf_val(tstart + tid, sRow, shxm), &xfb[tstart + tid]);
    }
}

extern "C" void kernel_launch(void* const* d_in, const int* in_sizes, int n_in,
                              void* d_out, int out_size, void* d_ws, size_t ws_size,
                              hipStream_t stream) {
    const float* x    = (const float*)d_in[0];
    const float* mask = (const float*)d_in[1];
    const float* Wg   = (const float*)d_in[2];

    const int  P  = in_sizes[0] / PATCH;    // 65536
    const int  NB = P / PPB;                // 2048
    const long T  = (long)out_size / 165;   // total children (fixed inputs)

    int* flags = (int*)d_ws;  // poison 0xAA / zeros both decode as "not ready"

    float* out = (float*)d_out;
    float* o_newx = out;
    float* o_newm = out + T * 32;
    float* o_size = out + T * 64;
    float* o_w    = out + T * 65;
    float* o_eidx = out + T * 67;
    float* o_xf   = out + T * 69;

    hipLaunchKernelGGL(k_fused, dim3(NB), dim3(256), 0, stream,
                       x, mask, Wg, flags, T,
                       o_newx, o_newm, o_size, o_w, o_eidx, o_xf);
}